// Round 1
// baseline (46.668 us; speedup 1.0000x reference)
//
#include <hip/hip_runtime.h>

#define BATCH 4
#define NROWS 2048
#define IN_DIM 1024
#define OUT_DIM 512
#define CH 64                 // y-partial chunks per batch
#define ROWS_PER_CH (NROWS / CH)   // 32

// ---------------- K1: w2[i] = sum_d fc_w[d][i] * a2[d] ----------------
__global__ void k1_w2(const float* __restrict__ fc_w,
                      const float* __restrict__ attn_w,
                      float* __restrict__ w2) {
    int i = blockIdx.x * 256 + threadIdx.x;      // 0..1023
    float acc = 0.f;
    for (int d = 0; d < OUT_DIM; ++d)
        acc += fc_w[(size_t)d * IN_DIM + i] * attn_w[OUT_DIM + d];
    w2[i] = acc;
}

// ---------------- K2: s2[row] = dot(x[row,:], w2) --------------------
__global__ void k2_s2(const float* __restrict__ x,
                      const float* __restrict__ w2,
                      float* __restrict__ s2) {
    int wave = (blockIdx.x * blockDim.x + threadIdx.x) >> 6;  // 0..8191
    int lane = threadIdx.x & 63;
    const float4* xr = (const float4*)(x + (size_t)wave * IN_DIM);
    const float4* w4 = (const float4*)w2;
    float acc = 0.f;
#pragma unroll
    for (int k = 0; k < 4; ++k) {
        float4 a = xr[lane + k * 64];
        float4 b = w4[lane + k * 64];
        acc += a.x * b.x + a.y * b.y + a.z * b.z + a.w * b.w;
    }
    for (int off = 32; off; off >>= 1) acc += __shfl_down(acc, off, 64);
    if (lane == 0) s2[wave] = acc;
}

// ------ K3: per-(batch,chunk) weighted partial sum of x rows ---------
// Each block recomputes the batch softmax stats from s2 (cheap), then
// accumulates y_partial[b][ch][i] = sum_{n in chunk} w[b,n] * x[b,n,i].
__global__ void k3_ypart(const float* __restrict__ x,
                         const float* __restrict__ s2,
                         float* __restrict__ ypart) {
    int b  = blockIdx.x / CH;
    int ch = blockIdx.x % CH;
    int t  = threadIdx.x;                // 0..255
    __shared__ float red[256];
    __shared__ float wgt[ROWS_PER_CH];

    const float* s2b = s2 + b * NROWS;
    float lv[8];
    float lm = -1e30f;
#pragma unroll
    for (int j = 0; j < 8; ++j) {
        lv[j] = s2b[t + j * 256];
        lm = fmaxf(lm, lv[j]);
    }
    red[t] = lm; __syncthreads();
    for (int o = 128; o; o >>= 1) {
        if (t < o) red[t] = fmaxf(red[t], red[t + o]);
        __syncthreads();
    }
    float m = red[0]; __syncthreads();
    float ls = 0.f;
#pragma unroll
    for (int j = 0; j < 8; ++j) ls += __expf(lv[j] - m);
    red[t] = ls; __syncthreads();
    for (int o = 128; o; o >>= 1) {
        if (t < o) red[t] += red[t + o];
        __syncthreads();
    }
    float inv = 1.f / red[0];

    int n0 = ch * ROWS_PER_CH;
    if (t < ROWS_PER_CH) wgt[t] = __expf(s2b[n0 + t] - m) * inv;
    __syncthreads();

    float acc[4] = {0.f, 0.f, 0.f, 0.f};
    const float* xb = x + ((size_t)b * NROWS + n0) * IN_DIM;
    for (int r = 0; r < ROWS_PER_CH; ++r) {
        float wr = wgt[r];
#pragma unroll
        for (int j = 0; j < 4; ++j)
            acc[j] += wr * xb[(size_t)r * IN_DIM + t + j * 256];
    }
    float* yp = ypart + ((size_t)b * CH + ch) * IN_DIM;
#pragma unroll
    for (int j = 0; j < 4; ++j) yp[t + j * 256] = acc[j];
}

// ---------------- K4: y[b][i] = sum_ch ypart[b][ch][i] ----------------
__global__ void k4_yred(const float* __restrict__ ypart,
                        float* __restrict__ y) {
    int idx = blockIdx.x * 256 + threadIdx.x;   // 0..4095
    int b = idx >> 10, i = idx & 1023;
    float acc = 0.f;
    for (int ch = 0; ch < CH; ++ch)
        acc += ypart[((size_t)b * CH + ch) * IN_DIM + i];
    y[idx] = acc;
}

// ---------------- K5: c[b][d] = dot(y[b,:], fc_w[d,:]) + fc_b[d] ------
__global__ void k5_c(const float* __restrict__ y,
                     const float* __restrict__ fc_w,
                     const float* __restrict__ fc_b,
                     float* __restrict__ c) {
    int wave = (blockIdx.x * blockDim.x + threadIdx.x) >> 6;  // 0..2047
    int lane = threadIdx.x & 63;
    int b = wave >> 9, d = wave & 511;
    const float4* wr = (const float4*)(fc_w + (size_t)d * IN_DIM);
    const float4* yr = (const float4*)(y + (size_t)b * IN_DIM);
    float acc = 0.f;
#pragma unroll
    for (int k = 0; k < 4; ++k) {
        float4 a  = wr[lane + k * 64];
        float4 bb = yr[lane + k * 64];
        acc += a.x * bb.x + a.y * bb.y + a.z * bb.z + a.w * bb.w;
    }
    for (int off = 32; off; off >>= 1) acc += __shfl_down(acc, off, 64);
    if (lane == 0) c[wave] = acc + fc_b[d];
}

// ---------------- K6: out[b,n,:] = c[b,:] broadcast -------------------
__global__ void k6_bcast(const float* __restrict__ c,
                         float4* __restrict__ out) {
    int fi = blockIdx.x * blockDim.x + threadIdx.x;  // float4 idx, 1M total
    int d4  = fi & 127;          // float4 within a 512-wide row
    int row = fi >> 7;           // b*NROWS + n
    int b   = row >> 11;
    out[fi] = ((const float4*)(c + (size_t)b * OUT_DIM))[d4];
}

extern "C" void kernel_launch(void* const* d_in, const int* in_sizes, int n_in,
                              void* d_out, int out_size, void* d_ws, size_t ws_size,
                              hipStream_t stream) {
    const float* x      = (const float*)d_in[0];
    const float* fc_w   = (const float*)d_in[1];
    const float* fc_b   = (const float*)d_in[2];
    const float* attn_w = (const float*)d_in[3];
    // attn_b (d_in[4]) cancels in the softmax — unused.

    float* ws    = (float*)d_ws;
    float* w2    = ws;                          // 1024
    float* s2    = ws + 1024;                   // 8192
    float* ypart = ws + 1024 + BATCH * NROWS;   // 4*64*1024 = 262144
    float* y     = ypart + (size_t)BATCH * CH * IN_DIM;  // 4096
    float* c     = y + (size_t)BATCH * IN_DIM;  // 2048
    float* out   = (float*)d_out;

    k1_w2   <<<IN_DIM / 256, 256, 0, stream>>>(fc_w, attn_w, w2);
    k2_s2   <<<(BATCH * NROWS) / 4, 256, 0, stream>>>(x, w2, s2);
    k3_ypart<<<BATCH * CH, 256, 0, stream>>>(x, s2, ypart);
    k4_yred <<<(BATCH * IN_DIM) / 256, 256, 0, stream>>>(ypart, y);
    k5_c    <<<(BATCH * OUT_DIM) / 4, 256, 0, stream>>>(y, fc_w, fc_b, c);
    k6_bcast<<<(BATCH * NROWS * OUT_DIM / 4) / 256, 256, 0, stream>>>(c, (float4*)out);
}